// Round 3
// baseline (136.999 us; speedup 1.0000x reference)
//
#include <hip/hip_runtime.h>
#include <stdint.h>

// UnfoldConv1d: y[b,o,t] = bias[o] + sum_j sum_c W[o, j*512+c] * x[b,c,t-2+j]
// bf16 MFMA GEMM, 256x256 tile, BK=64, 8 waves (2Mx4N).
// v3: 8-phase with BOTH pipelines counted: global_load_lds via counted vmcnt
// (T4) AND fragment ds_reads issued 1+ phase ahead with counted lgkmcnt, so
// LDS-pipe time hides under MFMA (R2's serialization was the regression).
// One barrier per phase; 2 A-banks + 2 B-banks of fragments.

typedef float    f32x4  __attribute__((ext_vector_type(4)));
typedef short    bf16x8 __attribute__((ext_vector_type(8)));

#define C_DIM   512
#define T_DIM   4096
#define TP_DIM  4104
#define OUT_DIM 512
#define KF_DIM  1536
#define B_DIM   8

__device__ __forceinline__ uint16_t f2bf(float f) {
  union { float f; uint32_t u; } v; v.f = f;
  uint32_t u = v.u;
  return (uint16_t)((u + 0x7fffu + ((u >> 16) & 1u)) >> 16);  // RNE
}

__device__ __forceinline__ void gload_lds16(const uint16_t* g, uint16_t* l) {
  __builtin_amdgcn_global_load_lds(
      (const __attribute__((address_space(1))) uint32_t*)g,
      (__attribute__((address_space(3))) uint32_t*)l, 16, 0, 0);
}

// Stage one 64-row slab (64 rows x 64 bf16 cols = 8KB): 1 load/thread.
// LDS dest linear (wave-uniform base + lane*16B); global src chunk
// pre-swizzled ch^=(row&7) so swizzled ds_reads see the right data.
__device__ __forceinline__ void stage_slab(const uint16_t* __restrict__ srcbase,
                                           int stride, uint16_t* lds, int r0,
                                           int tid) {
  int row = r0 + (tid >> 3);
  int ch = tid & 7;
  const uint16_t* src = srcbase + (long)row * stride + ((ch ^ (row & 7)) << 3);
  gload_lds16(src, lds + (long)(r0 * 64 + (tid >> 6) * 512));
}

#define BAR()   __builtin_amdgcn_s_barrier()
#define SBAR()  __builtin_amdgcn_sched_barrier(0)
#define LGKM(n) do { asm volatile("s_waitcnt lgkmcnt(" #n ")" ::: "memory"); SBAR(); } while (0)
#define VM(n)   asm volatile("s_waitcnt vmcnt(" #n ")" ::: "memory")
#define PRIO1() __builtin_amdgcn_s_setprio(1)
#define PRIO0() __builtin_amdgcn_s_setprio(0)

#define READ_A(dst, BUF, MH) do { \
  _Pragma("unroll") for (int mi = 0; mi < 4; ++mi) { \
    const int row_ = wm * 128 + (MH) * 64 + mi * 16 + lr; \
    _Pragma("unroll") for (int kk = 0; kk < 2; ++kk) \
      dst[mi][kk] = *(const bf16x8*)&(BUF)[row_ * 64 + (((kk * 4 + g) ^ (row_ & 7)) << 3)]; \
  } } while (0)

#define READ_B(dst, BUF, NH) do { \
  _Pragma("unroll") for (int ni = 0; ni < 2; ++ni) { \
    const int row_ = wn * 64 + (NH) * 32 + ni * 16 + lr; \
    _Pragma("unroll") for (int kk = 0; kk < 2; ++kk) \
      dst[ni][kk] = *(const bf16x8*)&(BUF)[row_ * 64 + (((kk * 4 + g) ^ (row_ & 7)) << 3)]; \
  } } while (0)

#define QUAD(A, B, MH, NH) do { PRIO1(); \
  _Pragma("unroll") for (int mi = 0; mi < 4; ++mi) \
  _Pragma("unroll") for (int ni = 0; ni < 2; ++ni) \
  _Pragma("unroll") for (int kk = 0; kk < 2; ++kk) \
    acc[(MH) * 4 + mi][(NH) * 2 + ni] = __builtin_amdgcn_mfma_f32_16x16x32_bf16( \
        A[mi][kk], B[ni][kk], acc[(MH) * 4 + mi][(NH) * 2 + ni], 0, 0, 0); \
  PRIO0(); } while (0)

// One iteration = 2 K-tiles: E=kb0 (buf0), O=kb0+1 (buf1). Stages tiles
// kb0+1 (B slabs 2,3), kb0+2 (buf0) and kb0+3 (buf1). All fragment reads
// are 1-2 phases ahead of their MFMA; lgkm(n) counts just-issued reads.
// Quadrant order: E: (0,0)(0,1)(1,1)(1,0); O: (0,1)(0,0)(1,0)(1,1).
template<bool FULL>
__device__ __forceinline__ void iter8(
    f32x4 (&acc)[8][4],
    bf16x8 (&a0)[4][2], bf16x8 (&a1)[4][2],
    bf16x8 (&b0)[2][2], bf16x8 (&b1)[2][2],
    uint16_t* LA0, uint16_t* LB0, uint16_t* LA1, uint16_t* LB1,
    const uint16_t* __restrict__ wsrc, const uint16_t* __restrict__ xsrc,
    int kb0, int tid, int wm, int wn, int lr, int g) {
  const uint16_t* bO1 = xsrc + ((kb0 + 1) >> 3) * C_DIM + (((kb0 + 1) & 7) << 6);
  const uint16_t* aE = wsrc + (kb0 + 2) * 64;
  const uint16_t* aO = wsrc + (kb0 + 3) * 64;
  const uint16_t* bE = xsrc + ((kb0 + 2) >> 3) * C_DIM + (((kb0 + 2) & 7) << 6);
  const uint16_t* bO = xsrc + ((kb0 + 3) >> 3) * C_DIM + (((kb0 + 3) & 7) << 6);

  // p1: MFMA E(0,0)=a0*b0 | read b1<-LB0.NH1 (4) | stage LB1 slabs 2,3 (tile O)
  BAR();
  READ_B(b1, LB0, 1);
  stage_slab(bO1, C_DIM, LB1, 128, tid); stage_slab(bO1, C_DIM, LB1, 192, tid);
  LGKM(4);
  QUAD(a0, b0, 0, 0);
  VM(8);
  // p2: E(0,1)=a0*b1 | read a1<-LA0.MH1 (8) | stage LA0 slabs 0,2 <- tile E'
  BAR();
  READ_A(a1, LA0, 1);
  if (FULL) { stage_slab(aE, KF_DIM, LA0, 0, tid); stage_slab(aE, KF_DIM, LA0, 128, tid); }
  LGKM(8);
  QUAD(a0, b1, 0, 1);
  if (FULL) VM(8); else VM(6);
  // p3: E(1,1)=a1*b1 | read a0<-LA1.MH0 (8) | stage LB0 slabs 0,1 <- E'
  BAR();
  READ_A(a0, LA1, 0);
  if (FULL) { stage_slab(bE, C_DIM, LB0, 0, tid); stage_slab(bE, C_DIM, LB0, 64, tid); }
  LGKM(8);
  QUAD(a1, b1, 1, 1);
  if (FULL) VM(4); else VM(0);
  // p4: E(1,0)=a1*b0 | read b1<-LB1.NH1 (4) | stage LB0 slabs 2,3 <- E'
  BAR();
  READ_B(b1, LB1, 1);
  if (FULL) { stage_slab(bE, C_DIM, LB0, 128, tid); stage_slab(bE, C_DIM, LB0, 192, tid); }
  LGKM(4);
  QUAD(a1, b0, 1, 0);
  // p5: O(0,1)=a0*b1 | read b0<-LB1.NH0 (4) | stage LA0 slabs 1,3 <- E'
  BAR();
  READ_B(b0, LB1, 0);
  if (FULL) { stage_slab(aE, KF_DIM, LA0, 64, tid); stage_slab(aE, KF_DIM, LA0, 192, tid); }
  LGKM(4);
  QUAD(a0, b1, 0, 1);
  // p6: O(0,0)=a0*b0 | read a1<-LA1.MH1 (8) | stage LA1 slabs 0,2 <- O'
  BAR();
  READ_A(a1, LA1, 1);
  if (FULL) { stage_slab(aO, KF_DIM, LA1, 0, tid); stage_slab(aO, KF_DIM, LA1, 128, tid); }
  LGKM(8);
  QUAD(a0, b0, 0, 0);
  if (FULL) VM(8);
  // p7: O(1,0)=a1*b0 | read a0<-LA0.MH0 (8, tile E') | stage LB1 slabs 0,1 <- O'
  BAR();
  if (FULL) {
    READ_A(a0, LA0, 0);
    stage_slab(bO, C_DIM, LB1, 0, tid); stage_slab(bO, C_DIM, LB1, 64, tid);
    LGKM(8);
  } else {
    LGKM(0);
  }
  QUAD(a1, b0, 1, 0);
  if (FULL) VM(6);
  // p8: O(1,1)=a1*b1 | read b0<-LB0.NH0 (4, tile E') | stage LA1 slabs 1,3 <- O'
  BAR();
  if (FULL) {
    READ_B(b0, LB0, 0);
    stage_slab(aO, KF_DIM, LA1, 64, tid); stage_slab(aO, KF_DIM, LA1, 192, tid);
    LGKM(4);
  } else {
    LGKM(0);
  }
  QUAD(a1, b1, 1, 1);
}

// grid (T/256=16, OUT/256=2, B=8), 512 threads = 8 waves (2M x 4N).
__global__ __launch_bounds__(512, 2) void gemm_kernel(
    const uint16_t* __restrict__ xp, const uint16_t* __restrict__ Wb,
    const float* __restrict__ bias, float* __restrict__ out) {
  __shared__ __align__(16) uint16_t LA0[256 * 64];
  __shared__ __align__(16) uint16_t LB0[256 * 64];
  __shared__ __align__(16) uint16_t LA1[256 * 64];
  __shared__ __align__(16) uint16_t LB1[256 * 64];

  const int tid  = threadIdx.x;
  const int lane = tid & 63;
  const int wid  = tid >> 6;
  const int wm   = wid >> 2;     // 0..1  (o / A side, 128 rows)
  const int wn   = wid & 3;      // 0..3  (t / B side, 64 rows)
  const int lr   = lane & 15;
  const int g    = lane >> 4;
  const int t0 = blockIdx.x * 256;
  const int o0 = blockIdx.y * 256;
  const int b  = blockIdx.z;

  const uint16_t* wsrc = Wb + (long)o0 * KF_DIM;
  const uint16_t* xsrc = xp + ((long)b * TP_DIM + t0) * C_DIM;

  f32x4 acc[8][4];
  #pragma unroll
  for (int mi = 0; mi < 8; ++mi)
    #pragma unroll
    for (int ni = 0; ni < 4; ++ni)
      #pragma unroll
      for (int r = 0; r < 4; ++r) acc[mi][ni][r] = 0.0f;

  bf16x8 a0[4][2], a1[4][2], b0r[2][2], b1r[2][2];

  // ---- prologue: tile0 -> buf0, tile1 partial -> buf1 ----
  // early: LA0 slabs 0,2 + LB0 all (6 loads), drain, then the "p7/p8-top"
  // fragment reads, then the steady-state in-flight set (8 loads).
  stage_slab(wsrc, KF_DIM, LA0, 0, tid);   stage_slab(wsrc, KF_DIM, LA0, 128, tid);
  stage_slab(xsrc, C_DIM, LB0, 0, tid);    stage_slab(xsrc, C_DIM, LB0, 64, tid);
  stage_slab(xsrc, C_DIM, LB0, 128, tid);  stage_slab(xsrc, C_DIM, LB0, 192, tid);
  VM(0);
  BAR();
  READ_A(a0, LA0, 0);        // tile0 MH0
  READ_B(b0r, LB0, 0);       // tile0 NH0
  stage_slab(wsrc, KF_DIM, LA0, 64, tid);  stage_slab(wsrc, KF_DIM, LA0, 192, tid);
  {
    const uint16_t* a1p = wsrc + 64;
    const uint16_t* b1p = xsrc + 64;       // tile1: j=0, c0=64
    stage_slab(a1p, KF_DIM, LA1, 0, tid);  stage_slab(a1p, KF_DIM, LA1, 128, tid);
    stage_slab(b1p, C_DIM, LB1, 0, tid);   stage_slab(b1p, C_DIM, LB1, 64, tid);
    stage_slab(a1p, KF_DIM, LA1, 64, tid); stage_slab(a1p, KF_DIM, LA1, 192, tid);
  }

  // ---- main loop: 24 K-tiles = 11 full iterations + 1 drain ----
  #pragma unroll 1
  for (int i = 0; i < 11; ++i)
    iter8<true>(acc, a0, a1, b0r, b1r, LA0, LB0, LA1, LB1, wsrc, xsrc,
                2 * i, tid, wm, wn, lr, g);
  iter8<false>(acc, a0, a1, b0r, b1r, LA0, LB0, LA1, LB1, wsrc, xsrc,
               22, tid, wm, wn, lr, g);

  // ---- epilogue: D col=lane&15 (t), row=(lane>>4)*4+r (o) ----
  #pragma unroll
  for (int mi = 0; mi < 8; ++mi) {
    int orow = o0 + wm * 128 + mi * 16 + (lane >> 4) * 4;
    #pragma unroll
    for (int ni = 0; ni < 4; ++ni) {
      int t = t0 + wn * 64 + ni * 16 + lr;
      float* op = out + ((long)b * OUT_DIM + orow) * T_DIM + t;
      #pragma unroll
      for (int r = 0; r < 4; ++r)
        op[(long)r * T_DIM] = acc[mi][ni][r] + bias[orow + r];
    }
  }
}

// ---------------- prep: W fp32 [512][1536] -> bf16 same layout ----------------
__global__ __launch_bounds__(256) void prep_w(const float* __restrict__ W,
                                              uint16_t* __restrict__ Wb) {
  int i = blockIdx.x * 256 + threadIdx.x;
  if (i >= 196608) return;
  float4 v = ((const float4*)W)[i];
  ushort4 o;
  o.x = f2bf(v.x); o.y = f2bf(v.y); o.z = f2bf(v.z); o.w = f2bf(v.w);
  ((ushort4*)Wb)[i] = o;
}

// ------ prep: x fp32 [b][c][t] -> xp bf16 [b][tp][c], tp=t+2, TP=4104 --------
__global__ __launch_bounds__(256) void prep_x(const float* __restrict__ x,
                                              uint16_t* __restrict__ xp) {
  __shared__ uint16_t tile[64 * 66];
  const int tid = threadIdx.x;
  const int tp0 = blockIdx.x * 64;
  const int c0  = blockIdx.y * 64;
  const int b   = blockIdx.z;
  #pragma unroll
  for (int it = 0; it < 8; ++it) {
    int u = it * 256 + tid;
    int crow = u >> 5;
    int p = u & 31;
    int t = tp0 - 2 + p * 2;
    float vx = 0.f, vy = 0.f;
    if (t >= 0 && t < T_DIM) {
      const float2 v = *(const float2*)(x + (long)(b * C_DIM + c0 + crow) * T_DIM + t);
      vx = v.x; vy = v.y;
    }
    tile[(2 * p) * 66 + crow]     = f2bf(vx);
    tile[(2 * p + 1) * 66 + crow] = f2bf(vy);
  }
  __syncthreads();
  #pragma unroll
  for (int it = 0; it < 8; ++it) {
    int u = it * 256 + tid;
    int tl = u >> 5;
    int q = u & 31;
    int tp = tp0 + tl;
    if (tp < TP_DIM) {
      ushort2 val;
      val.x = tile[tl * 66 + 2 * q];
      val.y = tile[tl * 66 + 2 * q + 1];
      *(ushort2*)(xp + (long)(b * TP_DIM + tp) * C_DIM + c0 + 2 * q) = val;
    }
  }
}

// ------------------------- naive fallback (no ws) ----------------------------
__global__ __launch_bounds__(256) void naive_kernel(const float* __restrict__ x,
                                                    const float* __restrict__ W,
                                                    const float* __restrict__ bias,
                                                    float* __restrict__ y) {
  int t = blockIdx.x * 256 + threadIdx.x;
  int o = blockIdx.y, b = blockIdx.z;
  float s = bias[o];
  #pragma unroll
  for (int j = 0; j < 3; ++j) {
    int tt = t - 2 + j;
    if (tt < 0) continue;
    const float* xr = x + (long)b * C_DIM * T_DIM + tt;
    const float* wr = W + (long)o * KF_DIM + j * C_DIM;
    float a = 0.f;
    for (int c = 0; c < C_DIM; ++c) a += wr[c] * xr[(long)c * T_DIM];
    s += a;
  }
  y[((long)b * OUT_DIM + o) * T_DIM + t] = s;
}

extern "C" void kernel_launch(void* const* d_in, const int* in_sizes, int n_in,
                              void* d_out, int out_size, void* d_ws, size_t ws_size,
                              hipStream_t stream) {
  (void)in_sizes; (void)n_in; (void)out_size;
  const float* x    = (const float*)d_in[0];
  const float* W    = (const float*)d_in[1];
  const float* bias = (const float*)d_in[2];
  float* out = (float*)d_out;

  const size_t wb_elems = (size_t)OUT_DIM * KF_DIM;          // 786432
  const size_t xp_elems = (size_t)B_DIM * TP_DIM * C_DIM;    // 16809984
  const size_t need = (wb_elems + xp_elems) * sizeof(uint16_t);

  if (ws_size < need) {  // insurance: slow but correct
    naive_kernel<<<dim3(T_DIM / 256, OUT_DIM, B_DIM), 256, 0, stream>>>(x, W, bias, out);
    return;
  }

  uint16_t* Wb = (uint16_t*)d_ws;
  uint16_t* xp = (uint16_t*)d_ws + wb_elems;

  prep_w<<<768, 256, 0, stream>>>(W, Wb);
  prep_x<<<dim3(65, 8, 8), 256, 0, stream>>>(x, xp);
  gemm_kernel<<<dim3(16, 2, 8), 512, 0, stream>>>(xp, Wb, bias, out);
}

// Round 4
// 87.708 us; speedup vs baseline: 1.5620x; 1.5620x over previous
//
#include <hip/hip_runtime.h>
#include <stdint.h>

// UnfoldConv1d: y[b,o,t] = bias[o] + sum_j sum_c W[o, j*512+c] * x[b,c,t-2+j]
// bf16 MFMA GEMM, 256x256 tile, BK=64, 8 waves (2Mx4N).
// v4: 8-phase pipelined schedule. Fragment ds_reads issued exactly 1 phase
// ahead (compiler inserts fine-grained lgkmcnt -- NO manual lgkm/sched_barrier,
// that was R3's regalloc poison). Counted vmcnt only (5 waits/iter, never 0).
// Banks: aX/aY (64 VGPR) + bX/bY (32 VGPR) + acc 128 (AGPR) fits 256 unified.

typedef float    f32x4  __attribute__((ext_vector_type(4)));
typedef short    bf16x8 __attribute__((ext_vector_type(8)));

#define C_DIM   512
#define T_DIM   4096
#define TP_DIM  4104
#define OUT_DIM 512
#define KF_DIM  1536
#define B_DIM   8

__device__ __forceinline__ uint16_t f2bf(float f) {
  union { float f; uint32_t u; } v; v.f = f;
  uint32_t u = v.u;
  return (uint16_t)((u + 0x7fffu + ((u >> 16) & 1u)) >> 16);  // RNE
}

__device__ __forceinline__ void gload_lds16(const uint16_t* g, uint16_t* l) {
  __builtin_amdgcn_global_load_lds(
      (const __attribute__((address_space(1))) uint32_t*)g,
      (__attribute__((address_space(3))) uint32_t*)l, 16, 0, 0);
}

// Stage one 64-row slab (64 rows x 64 bf16 = 8KB): 1 gload_lds/thread.
// srcRow0 = global base already offset to slab row 0. LDS dest linear;
// global src chunk pre-swizzled ch ^= (slabrow&7) (r0 multiple of 8 so
// absolute-row&7 == slabrow&7 == (tid>>3)&7).
template<int STRIDE>
__device__ __forceinline__ void stage_slab(const uint16_t* __restrict__ srcRow0,
                                           uint16_t* lds, int r0, int tid) {
  const uint16_t* src = srcRow0 + (tid >> 3) * STRIDE +
                        (((tid & 7) ^ ((tid >> 3) & 7)) << 3);
  gload_lds16(src, lds + r0 * 64 + (tid >> 6) * 512);
}

#define BAR()   __builtin_amdgcn_s_barrier()
#define VM(n)   asm volatile("s_waitcnt vmcnt(" #n ")" ::: "memory")
#define PRIO1() __builtin_amdgcn_s_setprio(1)
#define PRIO0() __builtin_amdgcn_s_setprio(0)

#define READ_A(dst, BUF, MH) do { \
  _Pragma("unroll") for (int mi = 0; mi < 4; ++mi) { \
    const int row_ = wm * 128 + (MH) * 64 + mi * 16 + lr; \
    _Pragma("unroll") for (int kk = 0; kk < 2; ++kk) \
      dst[mi][kk] = *(const bf16x8*)&(BUF)[row_ * 64 + (((kk * 4 + g) ^ (lr & 7)) << 3)]; \
  } } while (0)

#define READ_B(dst, BUF, NH) do { \
  _Pragma("unroll") for (int ni = 0; ni < 2; ++ni) { \
    const int row_ = wn * 64 + (NH) * 32 + ni * 16 + lr; \
    _Pragma("unroll") for (int kk = 0; kk < 2; ++kk) \
      dst[ni][kk] = *(const bf16x8*)&(BUF)[row_ * 64 + (((kk * 4 + g) ^ (lr & 7)) << 3)]; \
  } } while (0)

#define QUAD(A, B, MH, NH) do { PRIO1(); \
  _Pragma("unroll") for (int mi = 0; mi < 4; ++mi) \
  _Pragma("unroll") for (int ni = 0; ni < 2; ++ni) \
  _Pragma("unroll") for (int kk = 0; kk < 2; ++kk) \
    acc[(MH) * 4 + mi][(NH) * 2 + ni] = __builtin_amdgcn_mfma_f32_16x16x32_bf16( \
        A[mi][kk], B[ni][kk], acc[(MH) * 4 + mi][(NH) * 2 + ni], 0, 0, 0); \
  PRIO0(); } while (0)

// B-tile row0 pointer for K-tile kb: j = kb>>3 (time shift), c0 = (kb&7)*64.
__device__ __forceinline__ const uint16_t* btile(const uint16_t* xsrc, int kb) {
  return xsrc + (kb >> 3) * C_DIM + ((kb & 7) << 6);
}

// One iteration = 2 K-tiles: E=kb0 (buf0), O=kb0+1 (buf1).
// Quadrants (MH,NH): E p1-p4: (0,0)(0,1)(1,1)(1,0); O p5-p8 same.
// Banks: p1 aX bX | p2 aX bY | p3 aY bY | p4 aY bX |
//        p5 aX bY | p6 aX bX | p7 aY bX | p8 aY bY
// Phase-top reads (1 ahead): p1 bY<-E.NH1, p2 aY<-E.MH1, p3 aX<-O.MH0,
//   p4 bY<-O.NH0, p5 bX<-O.NH1, p6 aY<-O.MH1, p7 aX<-E'.MH0, p8 bX<-E'.NH0.
// Stages: p1 LB1{2,3}(O) | p2 LA0{0,2}(E') | p3 LB0{0,1}(E') | p4 LB0{2,3}(E')
//   | p5 LA0{1,3}(E') | p6 LA1{0,2}(O') | p7 LB1{0,1}(O') | p8 LA1{1,3}(O').
// vmcnt FIFO-sim: end-p1 VM(8), end-p2 VM(8), end-p3 VM(4), end-p6 VM(8),
//   end-p7 VM(6).  Drain iter: VM(8)/VM(6)/VM(0) at p1/p2/p3.
template<bool FULL>
__device__ __forceinline__ void iter8(
    f32x4 (&acc)[8][4],
    bf16x8 (&aX)[4][2], bf16x8 (&aY)[4][2],
    bf16x8 (&bX)[2][2], bf16x8 (&bY)[2][2],
    uint16_t* LA0, uint16_t* LB0, uint16_t* LA1, uint16_t* LB1,
    const uint16_t* __restrict__ wsrc, const uint16_t* __restrict__ xsrc,
    int kb0, int tid, int wm, int wn, int lr, int g) {
  const uint16_t* bO  = btile(xsrc, kb0 + 1);   // tile O B rows
  const uint16_t* aE2 = wsrc + (kb0 + 2) * 64;  // tile E' A
  const uint16_t* bE2 = btile(xsrc, kb0 + 2);   // tile E' B
  const uint16_t* aO2 = wsrc + (kb0 + 3) * 64;  // tile O' A
  const uint16_t* bO2 = btile(xsrc, kb0 + 3);   // tile O' B

  // p1: E(0,0) aX*bX | read bY<-LB0.NH1 | stage LB1{2,3}
  BAR();
  READ_B(bY, LB0, 1);
  stage_slab<C_DIM>(bO + 128 * C_DIM, LB1, 128, tid);
  stage_slab<C_DIM>(bO + 192 * C_DIM, LB1, 192, tid);
  QUAD(aX, bX, 0, 0);
  VM(8);
  // p2: E(0,1) aX*bY | read aY<-LA0.MH1 | stage LA0{0,2}
  BAR();
  READ_A(aY, LA0, 1);
  if (FULL) {
    stage_slab<KF_DIM>(aE2, LA0, 0, tid);
    stage_slab<KF_DIM>(aE2 + 128 * KF_DIM, LA0, 128, tid);
  }
  QUAD(aX, bY, 0, 1);
  if (FULL) { VM(8); } else { VM(6); }
  // p3: E(1,1) aY*bY | read aX<-LA1.MH0 | stage LB0{0,1}
  BAR();
  READ_A(aX, LA1, 0);
  if (FULL) {
    stage_slab<C_DIM>(bE2, LB0, 0, tid);
    stage_slab<C_DIM>(bE2 + 64 * C_DIM, LB0, 64, tid);
  }
  QUAD(aY, bY, 1, 1);
  if (FULL) { VM(4); } else { VM(0); }
  // p4: E(1,0) aY*bX | read bY<-LB1.NH0 | stage LB0{2,3}
  BAR();
  READ_B(bY, LB1, 0);
  if (FULL) {
    stage_slab<C_DIM>(bE2 + 128 * C_DIM, LB0, 128, tid);
    stage_slab<C_DIM>(bE2 + 192 * C_DIM, LB0, 192, tid);
  }
  QUAD(aY, bX, 1, 0);
  // p5: O(0,0) aX*bY | read bX<-LB1.NH1 | stage LA0{1,3}
  BAR();
  READ_B(bX, LB1, 1);
  if (FULL) {
    stage_slab<KF_DIM>(aE2 + 64 * KF_DIM, LA0, 64, tid);
    stage_slab<KF_DIM>(aE2 + 192 * KF_DIM, LA0, 192, tid);
  }
  QUAD(aX, bY, 0, 0);
  // p6: O(0,1) aX*bX | read aY<-LA1.MH1 | stage LA1{0,2}
  BAR();
  READ_A(aY, LA1, 1);
  if (FULL) {
    stage_slab<KF_DIM>(aO2, LA1, 0, tid);
    stage_slab<KF_DIM>(aO2 + 128 * KF_DIM, LA1, 128, tid);
  }
  QUAD(aX, bX, 0, 1);
  if (FULL) VM(8);
  // p7: O(1,1) aY*bX | read aX<-LA0.MH0 (E') | stage LB1{0,1}
  BAR();
  if (FULL) {
    READ_A(aX, LA0, 0);
    stage_slab<C_DIM>(bO2, LB1, 0, tid);
    stage_slab<C_DIM>(bO2 + 64 * C_DIM, LB1, 64, tid);
  }
  QUAD(aY, bX, 1, 1);
  if (FULL) VM(6);
  // p8: O(1,0) aY*bY | read bX<-LB0.NH0 (E') | stage LA1{1,3}
  BAR();
  if (FULL) {
    READ_B(bX, LB0, 0);
    stage_slab<KF_DIM>(aO2 + 64 * KF_DIM, LA1, 64, tid);
    stage_slab<KF_DIM>(aO2 + 192 * KF_DIM, LA1, 192, tid);
  }
  QUAD(aY, bY, 1, 0);
}

// grid (T/256=16, OUT/256=2, B=8), 512 threads = 8 waves (2M x 4N).
__global__ __launch_bounds__(512, 2) void gemm_kernel(
    const uint16_t* __restrict__ xp, const uint16_t* __restrict__ Wb,
    const float* __restrict__ bias, float* __restrict__ out) {
  __shared__ __align__(16) uint16_t LA0[256 * 64];
  __shared__ __align__(16) uint16_t LB0[256 * 64];
  __shared__ __align__(16) uint16_t LA1[256 * 64];
  __shared__ __align__(16) uint16_t LB1[256 * 64];

  const int tid  = threadIdx.x;
  const int lane = tid & 63;
  const int wid  = tid >> 6;
  const int wm   = wid >> 2;     // 0..1  (o / A side, 128 rows)
  const int wn   = wid & 3;      // 0..3  (t / B side, 64 rows)
  const int lr   = lane & 15;
  const int g    = lane >> 4;
  const int t0 = blockIdx.x * 256;
  const int o0 = blockIdx.y * 256;
  const int b  = blockIdx.z;

  const uint16_t* wsrc = Wb + (long)o0 * KF_DIM;
  const uint16_t* xsrc = xp + ((long)b * TP_DIM + t0) * C_DIM;

  f32x4 acc[8][4];
  #pragma unroll
  for (int mi = 0; mi < 8; ++mi)
    #pragma unroll
    for (int ni = 0; ni < 4; ++ni)
      #pragma unroll
      for (int r = 0; r < 4; ++r) acc[mi][ni][r] = 0.0f;

  bf16x8 aX[4][2], aY[4][2], bX[2][2], bY[2][2];

  // ---- prologue ----
  // Stage tile0 A{0,2} + B all (6 loads), drain, barrier, pre-read aX/bX,
  // then issue the steady-state in-flight set IN QUEUE ORDER:
  // [LA0{1,3}] [LA1{0,2}] [LB1{0,1}] [LA1{1,3}]  (= virtual p5,p6,p7,p8).
  {
    const uint16_t* a1 = wsrc + 64;        // tile1 A
    const uint16_t* b1 = btile(xsrc, 1);   // tile1 B
    stage_slab<KF_DIM>(wsrc, LA0, 0, tid);
    stage_slab<KF_DIM>(wsrc + 128 * KF_DIM, LA0, 128, tid);
    stage_slab<C_DIM>(xsrc, LB0, 0, tid);
    stage_slab<C_DIM>(xsrc + 64 * C_DIM, LB0, 64, tid);
    stage_slab<C_DIM>(xsrc + 128 * C_DIM, LB0, 128, tid);
    stage_slab<C_DIM>(xsrc + 192 * C_DIM, LB0, 192, tid);
    VM(0);
    BAR();
    READ_A(aX, LA0, 0);
    READ_B(bX, LB0, 0);
    stage_slab<KF_DIM>(wsrc + 64 * KF_DIM, LA0, 64, tid);
    stage_slab<KF_DIM>(wsrc + 192 * KF_DIM, LA0, 192, tid);
    stage_slab<KF_DIM>(a1, LA1, 0, tid);
    stage_slab<KF_DIM>(a1 + 128 * KF_DIM, LA1, 128, tid);
    stage_slab<C_DIM>(b1, LB1, 0, tid);
    stage_slab<C_DIM>(b1 + 64 * C_DIM, LB1, 64, tid);
    stage_slab<KF_DIM>(a1 + 64 * KF_DIM, LA1, 64, tid);
    stage_slab<KF_DIM>(a1 + 192 * KF_DIM, LA1, 192, tid);
  }

  // ---- main loop: 24 K-tiles = 11 full iterations + 1 drain ----
  #pragma unroll 1
  for (int i = 0; i < 11; ++i)
    iter8<true>(acc, aX, aY, bX, bY, LA0, LB0, LA1, LB1, wsrc, xsrc,
                2 * i, tid, wm, wn, lr, g);
  iter8<false>(acc, aX, aY, bX, bY, LA0, LB0, LA1, LB1, wsrc, xsrc,
               22, tid, wm, wn, lr, g);

  // ---- epilogue: D col=lane&15 (t), row=(lane>>4)*4+r (o) ----
  #pragma unroll
  for (int mi = 0; mi < 8; ++mi) {
    int orow = o0 + wm * 128 + mi * 16 + (lane >> 4) * 4;
    #pragma unroll
    for (int ni = 0; ni < 4; ++ni) {
      int t = t0 + wn * 64 + ni * 16 + lr;
      float* op = out + ((long)b * OUT_DIM + orow) * T_DIM + t;
      #pragma unroll
      for (int r = 0; r < 4; ++r)
        op[(long)r * T_DIM] = acc[mi][ni][r] + bias[orow + r];
    }
  }
}

// ---------------- prep: W fp32 [512][1536] -> bf16 same layout ----------------
__global__ __launch_bounds__(256) void prep_w(const float* __restrict__ W,
                                              uint16_t* __restrict__ Wb) {
  int i = blockIdx.x * 256 + threadIdx.x;
  if (i >= 196608) return;
  float4 v = ((const float4*)W)[i];
  ushort4 o;
  o.x = f2bf(v.x); o.y = f2bf(v.y); o.z = f2bf(v.z); o.w = f2bf(v.w);
  ((ushort4*)Wb)[i] = o;
}

// ------ prep: x fp32 [b][c][t] -> xp bf16 [b][tp][c], tp=t+2, TP=4104 --------
__global__ __launch_bounds__(256) void prep_x(const float* __restrict__ x,
                                              uint16_t* __restrict__ xp) {
  __shared__ uint16_t tile[64 * 66];
  const int tid = threadIdx.x;
  const int tp0 = blockIdx.x * 64;
  const int c0  = blockIdx.y * 64;
  const int b   = blockIdx.z;
  #pragma unroll
  for (int it = 0; it < 8; ++it) {
    int u = it * 256 + tid;
    int crow = u >> 5;
    int p = u & 31;
    int t = tp0 - 2 + p * 2;
    float vx = 0.f, vy = 0.f;
    if (t >= 0 && t < T_DIM) {
      const float2 v = *(const float2*)(x + (long)(b * C_DIM + c0 + crow) * T_DIM + t);
      vx = v.x; vy = v.y;
    }
    tile[(2 * p) * 66 + crow]     = f2bf(vx);
    tile[(2 * p + 1) * 66 + crow] = f2bf(vy);
  }
  __syncthreads();
  #pragma unroll
  for (int it = 0; it < 8; ++it) {
    int u = it * 256 + tid;
    int tl = u >> 5;
    int q = u & 31;
    int tp = tp0 + tl;
    if (tp < TP_DIM) {
      ushort2 val;
      val.x = tile[tl * 66 + 2 * q];
      val.y = tile[tl * 66 + 2 * q + 1];
      *(ushort2*)(xp + (long)(b * TP_DIM + tp) * C_DIM + c0 + 2 * q) = val;
    }
  }
}

// ------------------------- naive fallback (no ws) ----------------------------
__global__ __launch_bounds__(256) void naive_kernel(const float* __restrict__ x,
                                                    const float* __restrict__ W,
                                                    const float* __restrict__ bias,
                                                    float* __restrict__ y) {
  int t = blockIdx.x * 256 + threadIdx.x;
  int o = blockIdx.y, b = blockIdx.z;
  float s = bias[o];
  #pragma unroll
  for (int j = 0; j < 3; ++j) {
    int tt = t - 2 + j;
    if (tt < 0) continue;
    const float* xr = x + (long)b * C_DIM * T_DIM + tt;
    const float* wr = W + (long)o * KF_DIM + j * C_DIM;
    float a = 0.f;
    for (int c = 0; c < C_DIM; ++c) a += wr[c] * xr[(long)c * T_DIM];
    s += a;
  }
  y[((long)b * OUT_DIM + o) * T_DIM + t] = s;
}

extern "C" void kernel_launch(void* const* d_in, const int* in_sizes, int n_in,
                              void* d_out, int out_size, void* d_ws, size_t ws_size,
                              hipStream_t stream) {
  (void)in_sizes; (void)n_in; (void)out_size;
  const float* x    = (const float*)d_in[0];
  const float* W    = (const float*)d_in[1];
  const float* bias = (const float*)d_in[2];
  float* out = (float*)d_out;

  const size_t wb_elems = (size_t)OUT_DIM * KF_DIM;          // 786432
  const size_t xp_elems = (size_t)B_DIM * TP_DIM * C_DIM;    // 16809984
  const size_t need = (wb_elems + xp_elems) * sizeof(uint16_t);

  if (ws_size < need) {  // insurance: slow but correct
    naive_kernel<<<dim3(T_DIM / 256, OUT_DIM, B_DIM), 256, 0, stream>>>(x, W, bias, out);
    return;
  }

  uint16_t* Wb = (uint16_t*)d_ws;
  uint16_t* xp = (uint16_t*)d_ws + wb_elems;

  prep_w<<<768, 256, 0, stream>>>(W, Wb);
  prep_x<<<dim3(65, 8, 8), 256, 0, stream>>>(x, xp);
  gemm_kernel<<<dim3(16, 2, 8), 512, 0, stream>>>(xp, Wb, bias, out);
}

// Round 5
// 83.266 us; speedup vs baseline: 1.6453x; 1.0533x over previous
//
#include <hip/hip_runtime.h>
#include <stdint.h>

// UnfoldConv1d: y[b,o,t] = bias[o] + sum_j sum_c W[o, j*512+c] * x[b,c,t-2+j]
// B=8, C=512, T=4096, OUT=512, K=3, D=1.
// v5: proven R1 GEMM (128x128 tile, 4 waves, j-reuse of XT, 906 TF measured)
// + rewritten prep_x (vectorized both sides, bf16-in-LDS transpose).

typedef float    f32x4  __attribute__((ext_vector_type(4)));
typedef short    bf16x8 __attribute__((ext_vector_type(8)));

#define C_DIM   512
#define T_DIM   4096
#define TP_DIM  4104
#define OUT_DIM 512
#define KF_DIM  1536
#define B_DIM   8

__device__ __forceinline__ uint16_t f2bf(float f) {
  union { float f; uint32_t u; } v; v.f = f;
  uint32_t u = v.u;
  return (uint16_t)((u + 0x7fffu + ((u >> 16) & 1u)) >> 16);  // RNE
}

__device__ __forceinline__ void gload_lds16(const uint16_t* g, uint16_t* l) {
  __builtin_amdgcn_global_load_lds(
      (const __attribute__((address_space(1))) uint32_t*)g,
      (__attribute__((address_space(3))) uint32_t*)l, 16, 0, 0);
}

// ---------------- prep: W fp32 [512][1536] -> bf16 same layout ----------------
__global__ __launch_bounds__(256) void prep_w(const float* __restrict__ W,
                                              uint16_t* __restrict__ Wb) {
  int i = blockIdx.x * 256 + threadIdx.x;  // float4 units: 786432/4 = 196608
  if (i >= 196608) return;
  float4 v = ((const float4*)W)[i];
  ushort4 o;
  o.x = f2bf(v.x); o.y = f2bf(v.y); o.z = f2bf(v.z); o.w = f2bf(v.w);
  ((ushort4*)Wb)[i] = o;
}

// ------ prep: x fp32 [b][c][t] -> xp bf16 [b][tp][c], tp=t+2, TP=4104 --------
// v2: 64 tp-rows x 128 c-cols per block. Read float2/lane (coalesced 256B
// segments per c-row), convert to bf16 BEFORE LDS, stride-65 ushort tile
// (write pattern 2-way = free), write ushort4/lane (8B, coalesced).
__global__ __launch_bounds__(256) void prep_x(const float* __restrict__ x,
                                              uint16_t* __restrict__ xp) {
  __shared__ uint16_t tile[128 * 65];  // [c 128][t 64], stride 65
  const int tid = threadIdx.x;
  const int tp0 = blockIdx.x * 64;   // 65 tiles; last covers 4096..4103
  const int c0  = blockIdx.y * 128;
  const int b   = blockIdx.z;

  // read phase: 128 c-rows x 32 float2; t = tp0 - 2 + 2p (pair valid or not)
  const int p = tid & 31;
  const int t = tp0 - 2 + p * 2;
  const bool ok = (t >= 0) && (t < T_DIM);
  #pragma unroll
  for (int it = 0; it < 16; ++it) {
    int cr = it * 8 + (tid >> 5);
    float vx = 0.f, vy = 0.f;
    if (ok) {
      const float2 v = *(const float2*)(x + (long)(b * C_DIM + c0 + cr) * T_DIM + t);
      vx = v.x; vy = v.y;
    }
    tile[cr * 65 + 2 * p]     = f2bf(vx);
    tile[cr * 65 + 2 * p + 1] = f2bf(vy);
  }
  __syncthreads();

  // write phase: 64 rows x 32 ushort4 = 2048 units; xp[tp0+r][c0+4q..+3]
  const int q = tid & 31;
  #pragma unroll
  for (int it = 0; it < 8; ++it) {
    int r = it * 8 + (tid >> 5);
    int tp = tp0 + r;
    if (tp < TP_DIM) {
      ushort4 val;
      val.x = tile[(4 * q + 0) * 65 + r];
      val.y = tile[(4 * q + 1) * 65 + r];
      val.z = tile[(4 * q + 2) * 65 + r];
      val.w = tile[(4 * q + 3) * 65 + r];
      *(ushort4*)(xp + (long)(b * TP_DIM + tp) * C_DIM + c0 + 4 * q) = val;
    }
  }
}

// ---------------------------- main GEMM kernel -------------------------------
// R1-proven: grid (32, 4, 8), 256 threads, 4 waves as 2x2 of 64x64.
__global__ __launch_bounds__(256) void gemm_kernel(const uint16_t* __restrict__ xp,
                                                   const uint16_t* __restrict__ Wb,
                                                   const float* __restrict__ bias,
                                                   float* __restrict__ out) {
  __shared__ uint16_t XT[136 * 64];  // [row=tp_local 0..135][c 64], swizzled
  __shared__ uint16_t WS[128 * 64];  // [row=o_local][c 64], swizzled

  const int tid  = threadIdx.x;
  const int lane = tid & 63;
  const int wid  = tid >> 6;
  const int wm   = wid >> 1;     // wave row (0..1)
  const int wn   = wid & 1;      // wave col (0..1)
  const int t0 = blockIdx.x * 128;
  const int o0 = blockIdx.y * 128;
  const int b  = blockIdx.z;

  f32x4 acc[4][4];
  #pragma unroll
  for (int mi = 0; mi < 4; ++mi)
    #pragma unroll
    for (int ni = 0; ni < 4; ++ni)
      #pragma unroll
      for (int r = 0; r < 4; ++r) acc[mi][ni][r] = 0.0f;

  const uint16_t* xbase = xp + ((long)b * TP_DIM + t0) * C_DIM;
  const int g = lane >> 4;  // k-group 0..3 (8 consecutive k each)

  for (int c0 = 0; c0 < C_DIM; c0 += 64) {
    #pragma unroll
    for (int j = 0; j < 3; ++j) {
      __syncthreads();
      if (j == 0) {
        // stage XT: 136 rows x 8 chunks(16B); src chunk pre-swizzled
        #pragma unroll
        for (int it = 0; it < 4; ++it) {
          int u = it * 256 + tid;
          int row = u >> 3, ch = u & 7;
          const uint16_t* src = xbase + (long)row * C_DIM + c0 + ((ch ^ (row & 7)) << 3);
          gload_lds16(src, &XT[(it * 256 + wid * 64) * 8]);
        }
        if (tid < 64) {
          int u = 1024 + tid;
          int row = u >> 3, ch = u & 7;
          const uint16_t* src = xbase + (long)row * C_DIM + c0 + ((ch ^ (row & 7)) << 3);
          gload_lds16(src, &XT[1024 * 8]);
        }
      }
      // stage WS for this j: 128 rows x 8 chunks
      {
        const uint16_t* wbase = Wb + (long)o0 * KF_DIM + j * C_DIM + c0;
        #pragma unroll
        for (int it = 0; it < 4; ++it) {
          int u = it * 256 + tid;
          int row = u >> 3, ch = u & 7;
          const uint16_t* src = wbase + (long)row * KF_DIM + ((ch ^ (row & 7)) << 3);
          gload_lds16(src, &WS[(it * 256 + wid * 64) * 8]);
        }
      }
      __syncthreads();

      #pragma unroll
      for (int cc = 0; cc < 2; ++cc) {
        bf16x8 af[4], bfr[4];
        #pragma unroll
        for (int mi = 0; mi < 4; ++mi) {
          int row = wm * 64 + mi * 16 + (lane & 15);
          int chs = (cc * 4 + g) ^ (row & 7);
          af[mi] = *(const bf16x8*)&WS[row * 64 + chs * 8];
        }
        #pragma unroll
        for (int ni = 0; ni < 4; ++ni) {
          int row = wn * 64 + ni * 16 + (lane & 15) + j;  // tp_local = tn + j
          int chs = (cc * 4 + g) ^ (row & 7);
          bfr[ni] = *(const bf16x8*)&XT[row * 64 + chs * 8];
        }
        #pragma unroll
        for (int mi = 0; mi < 4; ++mi)
          #pragma unroll
          for (int ni = 0; ni < 4; ++ni)
            acc[mi][ni] = __builtin_amdgcn_mfma_f32_16x16x32_bf16(
                af[mi], bfr[ni], acc[mi][ni], 0, 0, 0);
      }
    }
  }

  // epilogue: D layout col=lane&15 (t), row=(lane>>4)*4+r (o)  [m89-verified]
  #pragma unroll
  for (int mi = 0; mi < 4; ++mi) {
    int orow = o0 + wm * 64 + mi * 16 + (lane >> 4) * 4;
    #pragma unroll
    for (int ni = 0; ni < 4; ++ni) {
      int t = t0 + wn * 64 + ni * 16 + (lane & 15);
      float* op = out + ((long)b * OUT_DIM + orow) * T_DIM + t;
      #pragma unroll
      for (int r = 0; r < 4; ++r)
        op[(long)r * T_DIM] = acc[mi][ni][r] + bias[orow + r];
    }
  }
}

// ------------------------- naive fallback (no ws) ----------------------------
__global__ __launch_bounds__(256) void naive_kernel(const float* __restrict__ x,
                                                    const float* __restrict__ W,
                                                    const float* __restrict__ bias,
                                                    float* __restrict__ y) {
  int t = blockIdx.x * 256 + threadIdx.x;
  int o = blockIdx.y, b = blockIdx.z;
  float s = bias[o];
  #pragma unroll
  for (int j = 0; j < 3; ++j) {
    int tt = t - 2 + j;
    if (tt < 0) continue;
    const float* xr = x + (long)b * C_DIM * T_DIM + tt;
    const float* wr = W + (long)o * KF_DIM + j * C_DIM;
    float a = 0.f;
    for (int c = 0; c < C_DIM; ++c) a += wr[c] * xr[(long)c * T_DIM];
    s += a;
  }
  y[((long)b * OUT_DIM + o) * T_DIM + t] = s;
}

extern "C" void kernel_launch(void* const* d_in, const int* in_sizes, int n_in,
                              void* d_out, int out_size, void* d_ws, size_t ws_size,
                              hipStream_t stream) {
  (void)in_sizes; (void)n_in; (void)out_size;
  const float* x    = (const float*)d_in[0];
  const float* W    = (const float*)d_in[1];
  const float* bias = (const float*)d_in[2];
  float* out = (float*)d_out;

  const size_t wb_elems = (size_t)OUT_DIM * KF_DIM;          // 786432
  const size_t xp_elems = (size_t)B_DIM * TP_DIM * C_DIM;    // 16809984
  const size_t need = (wb_elems + xp_elems) * sizeof(uint16_t);

  if (ws_size < need) {  // insurance: slow but correct
    naive_kernel<<<dim3(T_DIM / 256, OUT_DIM, B_DIM), 256, 0, stream>>>(x, W, bias, out);
    return;
  }

  uint16_t* Wb = (uint16_t*)d_ws;
  uint16_t* xp = (uint16_t*)d_ws + wb_elems;

  prep_w<<<768, 256, 0, stream>>>(W, Wb);
  prep_x<<<dim3(65, 4, 8), 256, 0, stream>>>(x, xp);
  gemm_kernel<<<dim3(32, 4, 8), 256, 0, stream>>>(xp, Wb, bias, out);
}